// Round 2
// baseline (5370.953 us; speedup 1.0000x reference)
//
#include <hip/hip_runtime.h>
#include <hip/hip_bf16.h>

// JointNet: logp = log_softmax(tanh(enc@We + b_e (+) dec@Wd + b_d) @ Wfc + b_fc), masked.
// B=4 T=256 U=64 V=1024 F=1024 K_proj=512.
//  k1: pack weights -> bf16 fragment-major [K/8][1024][8]
//  k2: MFMA projections pe/pd (fp32, in ws)
//  k3: main: block = t-PAIR (BM=128 rows = 2 t x 64 u), 1024 thr / 16 waves,
//      wave tile 64x128 mfma_32x32x16_bf16, T14 split staging (issue-early/
//      commit-late), double-buffered swizzled LDS A-tile, fused max-free
//      log-softmax epilogue.

#define TT 256
#define UU 64
#define VV 1024
#define FF 1024
#define DK 512

typedef __bf16 bf16x8 __attribute__((ext_vector_type(8)));
typedef float  f32x16 __attribute__((ext_vector_type(16)));

__device__ __forceinline__ float fast_tanh(float x) {
  float ax = __builtin_fabsf(x);
  float e  = __expf(-2.0f * ax);
  float r  = (1.0f - e) * __builtin_amdgcn_rcpf(1.0f + e);
  return __builtin_copysignf(r, x);
}

// ---------------- pack: W fp32 [K][1024] -> bf16 [K/8][1024][8] ----------------
__global__ __launch_bounds__(256)
void pack_w(const float* __restrict__ Wfc, const float* __restrict__ Wenc,
            const float* __restrict__ Wdec,
            __bf16* __restrict__ Pfc, __bf16* __restrict__ Pen, __bf16* __restrict__ Pde)
{
  int bi = blockIdx.x;
  const float* W; __bf16* P; int base;
  if (bi < 512)      { W = Wfc;  P = Pfc; base = bi; }
  else if (bi < 768) { W = Wenc; P = Pen; base = bi - 512; }
  else               { W = Wdec; P = Pde; base = bi - 768; }
  int idx = base * 256 + threadIdx.x;     // idx = k8*1024 + v
  int k8 = idx >> 10, v = idx & 1023;
  bf16x8 o;
#pragma unroll
  for (int j = 0; j < 8; ++j) o[j] = (__bf16)W[(k8 * 8 + j) * 1024 + v];
  *(bf16x8*)(P + (size_t)idx * 8) = o;
}

// ---------------- projections: pe = enc@We + be, pd = dec@Wd + bd --------------
__global__ __launch_bounds__(256)
void proj_mfma(const float* __restrict__ enc, const float* __restrict__ dec,
               const __bf16* __restrict__ Pen, const __bf16* __restrict__ Pde,
               const float* __restrict__ be, const float* __restrict__ bd,
               float* __restrict__ pe, float* __restrict__ pd)
{
  constexpr int BK = 128;
  __shared__ __align__(16) char As[2][64 * BK * 2];   // 32KB
  const int tid = threadIdx.x;
  const int lane = tid & 63;
  const int wid  = tid >> 6;        // 0..3
  const int l31  = lane & 31;
  const int lhi  = lane >> 5;

  int bi = blockIdx.x;
  const float* X; const __bf16* PW; const float* bias; float* P; int rt, ct;
  if (bi < 64) { X = enc; PW = Pen; bias = be; P = pe; rt = bi >> 2; ct = bi & 3; }
  else { int bj = bi - 64; X = dec; PW = Pde; bias = bd; P = pd; rt = bj >> 2; ct = bj & 3; }
  const int r0 = rt * 64;

  auto fillA = [&](int buf, int kc) {
#pragma unroll
    for (int i = 0; i < 4; ++i) {
      int tau = i * 256 + tid;
      int r = tau >> 4, g = tau & 15;
      int k = kc * BK + g * 8;
      const float4* x4 = (const float4*)(X + (r0 + r) * DK + k);
      float4 a0 = x4[0], a1 = x4[1];
      float xv[8] = {a0.x, a0.y, a0.z, a0.w, a1.x, a1.y, a1.z, a1.w};
      bf16x8 p;
#pragma unroll
      for (int q = 0; q < 8; ++q) p[q] = (__bf16)xv[q];
      *(bf16x8*)(&As[buf][r * (BK * 2) + ((g * 16) ^ ((r & 7) << 4))]) = p;
    }
  };

  f32x16 acc[2][2];
#pragma unroll
  for (int mi = 0; mi < 2; ++mi)
#pragma unroll
    for (int ni = 0; ni < 2; ++ni)
#pragma unroll
      for (int q = 0; q < 16; ++q) acc[mi][ni][q] = 0.f;

  fillA(0, 0);
  __syncthreads();
  const int colBase = ct * 256 + wid * 64 + l31;
  for (int kc = 0; kc < DK / BK; ++kc) {
    if (kc + 1 < DK / BK) fillA((kc + 1) & 1, kc + 1);
    const char* Ab = As[kc & 1];
#pragma unroll 2
    for (int ks = 0; ks < BK / 16; ++ks) {
      int k8 = (kc * 8 + ks) * 2 + lhi;
      bf16x8 bfr[2];
#pragma unroll
      for (int ni = 0; ni < 2; ++ni)
        bfr[ni] = *(const bf16x8*)(PW + ((size_t)k8 * VV + colBase + ni * 32) * 8);
      bf16x8 afr[2];
#pragma unroll
      for (int mi = 0; mi < 2; ++mi) {
        int ra = mi * 32 + l31;
        int kb = ks * 32 + lhi * 16;
        afr[mi] = *(const bf16x8*)(&Ab[ra * (BK * 2) + (kb ^ ((ra & 7) << 4))]);
      }
#pragma unroll
      for (int mi = 0; mi < 2; ++mi)
#pragma unroll
        for (int ni = 0; ni < 2; ++ni)
          acc[mi][ni] = __builtin_amdgcn_mfma_f32_32x32x16_bf16(afr[mi], bfr[ni], acc[mi][ni], 0, 0, 0);
    }
    __syncthreads();
  }
  float bv[2];
#pragma unroll
  for (int ni = 0; ni < 2; ++ni) bv[ni] = bias[colBase + ni * 32];
#pragma unroll
  for (int mi = 0; mi < 2; ++mi)
#pragma unroll
    for (int j = 0; j < 16; ++j) {
      int row = r0 + mi * 32 + (j & 3) + 8 * (j >> 2) + 4 * lhi;
#pragma unroll
      for (int ni = 0; ni < 2; ++ni)
        P[row * VV + colBase + ni * 32] = acc[mi][ni][j] + bv[ni];
    }
}

// ------- main: per t-pair block (BM=128), fused GEMM + log-softmax, T14 -------
__global__ __launch_bounds__(1024, 8)
void joint_main(const float* __restrict__ pe, const float* __restrict__ pd,
                const __bf16* __restrict__ pW, const float* __restrict__ bfc,
                const int* __restrict__ elens, const int* __restrict__ dlens,
                float* __restrict__ out)
{
  constexpr int BK = 128, BM = 128;
  __shared__ __align__(16) char As[2][BM * BK * 2];   // 64KB
  __shared__ float pr[8][BM];                          // 4KB
  __shared__ float lseS[BM];

  const int blk = blockIdx.x;        // 512 = b*128 + tpair
  const int b = blk >> 7;
  const int t0 = (blk & 127) << 1;
  const int tid = threadIdx.x;
  const int elen = elens[b], dlen = dlens[b];
  float* outBase = out + (size_t)(b * TT + t0) * (UU * VV);  // 2*64*1024 floats

  if (t0 >= elen) {                  // both t's masked (prefix mask) -> zeros
    float4 z = {0.f, 0.f, 0.f, 0.f};
#pragma unroll 4
    for (int i = tid; i < 2 * UU * VV / 4; i += 1024) ((float4*)outBase)[i] = z;
    return;
  }

  const int lane = tid & 63;
  const int wid  = tid >> 6;         // 0..15
  const int wr   = wid >> 3;         // 0..1  (row group: which t of the pair)
  const int wc   = wid & 7;          // 0..7  (col group)
  const int l31  = lane & 31;
  const int lhi  = lane >> 5;
  const int colLane = wc * 128 + l31;

  const float* peB = pe + (size_t)(b * TT + t0) * FF;
  const float* pdB = pd + (size_t)b * UU * FF;

  const int sr = tid >> 4;           // staging row (half 0: rows 0..63)
  const int sg = tid & 15;           // k-group of 8

  float4 R[4];
  auto issueH = [&](int kc, int half) {
    int r = sr + half * 64;
    int k = kc * BK + sg * 8;
    const float4* e4 = (const float4*)(peB + (r >> 6) * FF + k);
    const float4* d4 = (const float4*)(pdB + (r & 63) * FF + k);
    R[0] = e4[0]; R[1] = e4[1]; R[2] = d4[0]; R[3] = d4[1];
  };
  auto commitH = [&](int buf, int half) {
    int r = sr + half * 64;
    float hv[8] = {R[0].x + R[2].x, R[0].y + R[2].y, R[0].z + R[2].z, R[0].w + R[2].w,
                   R[1].x + R[3].x, R[1].y + R[3].y, R[1].z + R[3].z, R[1].w + R[3].w};
    bf16x8 p;
#pragma unroll
    for (int q = 0; q < 8; ++q) p[q] = (__bf16)fast_tanh(hv[q]);
    *(bf16x8*)(&As[buf][r * (BK * 2) + ((sg * 16) ^ ((r & 7) << 4))]) = p;
  };

  f32x16 acc[2][4];
#pragma unroll
  for (int mi = 0; mi < 2; ++mi)
#pragma unroll
    for (int ni = 0; ni < 4; ++ni)
#pragma unroll
      for (int q = 0; q < 16; ++q) acc[mi][ni][q] = 0.f;

  issueH(0, 0); commitH(0, 0);
  issueH(0, 1); commitH(0, 1);
  __syncthreads();

  auto mstep = [&](const char* Ab, int kc, int ks) {
    int k8 = (kc * 8 + ks) * 2 + lhi;
    bf16x8 bfr[4];
#pragma unroll
    for (int ni = 0; ni < 4; ++ni)
      bfr[ni] = *(const bf16x8*)(pW + ((size_t)k8 * VV + colLane + ni * 32) * 8);
    bf16x8 afr[2];
#pragma unroll
    for (int mi = 0; mi < 2; ++mi) {
      int ra = wr * 64 + mi * 32 + l31;
      int kb = ks * 32 + lhi * 16;
      afr[mi] = *(const bf16x8*)(&Ab[ra * (BK * 2) + (kb ^ ((ra & 7) << 4))]);
    }
#pragma unroll
    for (int mi = 0; mi < 2; ++mi)
#pragma unroll
      for (int ni = 0; ni < 4; ++ni)
        acc[mi][ni] = __builtin_amdgcn_mfma_f32_32x32x16_bf16(afr[mi], bfr[ni], acc[mi][ni], 0, 0, 0);
  };

  for (int kc = 0; kc < FF / BK; ++kc) {   // 8 chunks
    const char* Ab = As[kc & 1];
    const int nb = (kc + 1) & 1;
    const bool more = (kc + 1) < FF / BK;
    if (more) issueH(kc + 1, 0);           // loads in flight over next 4 k-steps
#pragma unroll 2
    for (int ks = 0; ks < 4; ++ks) mstep(Ab, kc, ks);
    if (more) { commitH(nb, 0); issueH(kc + 1, 1); }
#pragma unroll 2
    for (int ks = 4; ks < 8; ++ks) mstep(Ab, kc, ks);
    if (more) commitH(nb, 1);
    __syncthreads();                       // one barrier per chunk
  }

  // bias + exp row-sums (max-free: |logit| <= 1024/32 + |b_fc| < 33, exp fits fp32)
  float bias[4];
#pragma unroll
  for (int ni = 0; ni < 4; ++ni) bias[ni] = bfc[colLane + ni * 32];

  float rsum[2][16];
#pragma unroll
  for (int mi = 0; mi < 2; ++mi)
#pragma unroll
    for (int j = 0; j < 16; ++j) {
      float s = 0.f;
#pragma unroll
      for (int ni = 0; ni < 4; ++ni) {
        float v = acc[mi][ni][j] + bias[ni];
        acc[mi][ni][j] = v;
        s += __expf(v);
      }
      rsum[mi][j] = s;
    }
#pragma unroll
  for (int s = 1; s < 32; s <<= 1) {
#pragma unroll
    for (int mi = 0; mi < 2; ++mi)
#pragma unroll
      for (int j = 0; j < 16; ++j)
        rsum[mi][j] += __shfl_xor(rsum[mi][j], s, 64);
  }
#pragma unroll
  for (int mi = 0; mi < 2; ++mi)
#pragma unroll
    for (int j = 0; j < 16; ++j)
      if (l31 == j) {
        int row = wr * 64 + mi * 32 + (j & 3) + 8 * (j >> 2) + 4 * lhi;
        pr[wc][row] = rsum[mi][j];
      }
  __syncthreads();
  if (tid < BM) {
    float s = 0.f;
#pragma unroll
    for (int w = 0; w < 8; ++w) s += pr[w][tid];
    lseS[tid] = __logf(s);
  }
  __syncthreads();

#pragma unroll
  for (int mi = 0; mi < 2; ++mi)
#pragma unroll
    for (int j = 0; j < 16; ++j) {
      int row = wr * 64 + mi * 32 + (j & 3) + 8 * (j >> 2) + 4 * lhi;
      float l = lseS[row];
      int tt = t0 + (row >> 6);
      bool valid = (tt < elen) && ((row & 63) < dlen);
#pragma unroll
      for (int ni = 0; ni < 4; ++ni) {
        float v = valid ? (acc[mi][ni][j] - l) : 0.0f;
        outBase[(size_t)row * VV + colLane + ni * 32] = v;
      }
    }
}

extern "C" void kernel_launch(void* const* d_in, const int* in_sizes, int n_in,
                              void* d_out, int out_size, void* d_ws, size_t ws_size,
                              hipStream_t stream)
{
  const float* enc  = (const float*)d_in[0];
  const float* dec  = (const float*)d_in[1];
  const float* Wenc = (const float*)d_in[2];
  const float* benc = (const float*)d_in[3];
  const float* Wdec = (const float*)d_in[4];
  const float* bdec = (const float*)d_in[5];
  const float* Wfc  = (const float*)d_in[6];
  const float* bfc  = (const float*)d_in[7];
  const int* elens  = (const int*)d_in[8];
  const int* dlens  = (const int*)d_in[9];
  float* out = (float*)d_out;

  float* pe = (float*)d_ws;                       // 1024*1024 f32
  float* pd = pe + 1024 * 1024;                   // 256*1024 f32
  __bf16* Pfc = (__bf16*)(pd + 256 * 1024);       // 1024*1024 bf16
  __bf16* Pen = Pfc + 1024 * 1024;                // 512*1024 bf16
  __bf16* Pde = Pen + 512 * 1024;                 // 512*1024 bf16

  pack_w<<<1024, 256, 0, stream>>>(Wfc, Wenc, Wdec, Pfc, Pen, Pde);
  proj_mfma<<<80, 256, 0, stream>>>(enc, dec, Pen, Pde, benc, bdec, pe, pd);
  joint_main<<<512, 1024, 0, stream>>>(pe, pd, Pfc, bfc, elens, dlens, out);
}

// Round 3
// 219.011 us; speedup vs baseline: 24.5236x; 24.5236x over previous
//
#include <hip/hip_runtime.h>
#include <hip/hip_bf16.h>

// JointNet: logp = log_softmax(tanh(enc@We + b_e (+) dec@Wd + b_d) @ Wfc + b_fc), masked.
// B=4 T=256 U=64 V=1024 F=1024 K_proj=512.
//  k1: pack weights -> bf16 fragment-major [K/8][1024][8]
//  k2: MFMA projections pe/pd (fp32, in ws)
//  k3: main: block = one (b,t), 512 thr / 8 waves, wave tile 64x128
//      (mfma_32x32x16_bf16, acc in AGPR), T14 issue-early/commit-late staging
//      of A = tanh(pe+pd) into double-buffered swizzled LDS, fused max-free
//      log-softmax epilogue.
// R2 lesson: NO aggressive min-waves launch_bounds — 64x128 wave tile needs
// 128 acc regs; (1024,8) forced 64-reg budget -> full spill -> 23x regression.

#define TT 256
#define UU 64
#define VV 1024
#define FF 1024
#define DK 512

typedef __bf16 bf16x8 __attribute__((ext_vector_type(8)));
typedef float  f32x16 __attribute__((ext_vector_type(16)));

__device__ __forceinline__ float fast_tanh(float x) {
  float ax = __builtin_fabsf(x);
  float e  = __expf(-2.0f * ax);
  float r  = (1.0f - e) * __builtin_amdgcn_rcpf(1.0f + e);
  return __builtin_copysignf(r, x);
}

// ---------------- pack: W fp32 [K][1024] -> bf16 [K/8][1024][8] ----------------
__global__ __launch_bounds__(256)
void pack_w(const float* __restrict__ Wfc, const float* __restrict__ Wenc,
            const float* __restrict__ Wdec,
            __bf16* __restrict__ Pfc, __bf16* __restrict__ Pen, __bf16* __restrict__ Pde)
{
  int bi = blockIdx.x;
  const float* W; __bf16* P; int base;
  if (bi < 512)      { W = Wfc;  P = Pfc; base = bi; }
  else if (bi < 768) { W = Wenc; P = Pen; base = bi - 512; }
  else               { W = Wdec; P = Pde; base = bi - 768; }
  int idx = base * 256 + threadIdx.x;     // idx = k8*1024 + v
  int k8 = idx >> 10, v = idx & 1023;
  bf16x8 o;
#pragma unroll
  for (int j = 0; j < 8; ++j) o[j] = (__bf16)W[(k8 * 8 + j) * 1024 + v];
  *(bf16x8*)(P + (size_t)idx * 8) = o;
}

// ---------------- projections: pe = enc@We + be, pd = dec@Wd + bd --------------
__global__ __launch_bounds__(256)
void proj_mfma(const float* __restrict__ enc, const float* __restrict__ dec,
               const __bf16* __restrict__ Pen, const __bf16* __restrict__ Pde,
               const float* __restrict__ be, const float* __restrict__ bd,
               float* __restrict__ pe, float* __restrict__ pd)
{
  constexpr int BK = 128;
  __shared__ __align__(16) char As[2][64 * BK * 2];   // 32KB
  const int tid = threadIdx.x;
  const int lane = tid & 63;
  const int wid  = tid >> 6;        // 0..3
  const int l31  = lane & 31;
  const int lhi  = lane >> 5;

  int bi = blockIdx.x;
  const float* X; const __bf16* PW; const float* bias; float* P; int rt, ct;
  if (bi < 64) { X = enc; PW = Pen; bias = be; P = pe; rt = bi >> 2; ct = bi & 3; }
  else { int bj = bi - 64; X = dec; PW = Pde; bias = bd; P = pd; rt = bj >> 2; ct = bj & 3; }
  const int r0 = rt * 64;

  auto fillA = [&](int buf, int kc) {
#pragma unroll
    for (int i = 0; i < 4; ++i) {
      int tau = i * 256 + tid;
      int r = tau >> 4, g = tau & 15;
      int k = kc * BK + g * 8;
      const float4* x4 = (const float4*)(X + (r0 + r) * DK + k);
      float4 a0 = x4[0], a1 = x4[1];
      float xv[8] = {a0.x, a0.y, a0.z, a0.w, a1.x, a1.y, a1.z, a1.w};
      bf16x8 p;
#pragma unroll
      for (int q = 0; q < 8; ++q) p[q] = (__bf16)xv[q];
      *(bf16x8*)(&As[buf][r * (BK * 2) + ((g * 16) ^ ((r & 7) << 4))]) = p;
    }
  };

  f32x16 acc[2][2];
#pragma unroll
  for (int mi = 0; mi < 2; ++mi)
#pragma unroll
    for (int ni = 0; ni < 2; ++ni)
#pragma unroll
      for (int q = 0; q < 16; ++q) acc[mi][ni][q] = 0.f;

  fillA(0, 0);
  __syncthreads();
  const int colBase = ct * 256 + wid * 64 + l31;
  for (int kc = 0; kc < DK / BK; ++kc) {
    if (kc + 1 < DK / BK) fillA((kc + 1) & 1, kc + 1);
    const char* Ab = As[kc & 1];
#pragma unroll 2
    for (int ks = 0; ks < BK / 16; ++ks) {
      int k8 = (kc * 8 + ks) * 2 + lhi;
      bf16x8 bfr[2];
#pragma unroll
      for (int ni = 0; ni < 2; ++ni)
        bfr[ni] = *(const bf16x8*)(PW + ((size_t)k8 * VV + colBase + ni * 32) * 8);
      bf16x8 afr[2];
#pragma unroll
      for (int mi = 0; mi < 2; ++mi) {
        int ra = mi * 32 + l31;
        int kb = ks * 32 + lhi * 16;
        afr[mi] = *(const bf16x8*)(&Ab[ra * (BK * 2) + (kb ^ ((ra & 7) << 4))]);
      }
#pragma unroll
      for (int mi = 0; mi < 2; ++mi)
#pragma unroll
        for (int ni = 0; ni < 2; ++ni)
          acc[mi][ni] = __builtin_amdgcn_mfma_f32_32x32x16_bf16(afr[mi], bfr[ni], acc[mi][ni], 0, 0, 0);
    }
    __syncthreads();
  }
  float bv[2];
#pragma unroll
  for (int ni = 0; ni < 2; ++ni) bv[ni] = bias[colBase + ni * 32];
#pragma unroll
  for (int mi = 0; mi < 2; ++mi)
#pragma unroll
    for (int j = 0; j < 16; ++j) {
      int row = r0 + mi * 32 + (j & 3) + 8 * (j >> 2) + 4 * lhi;
#pragma unroll
      for (int ni = 0; ni < 2; ++ni)
        P[row * VV + colBase + ni * 32] = acc[mi][ni][j] + bv[ni];
    }
}

// ------ main: per-(b,t) block, fused GEMM + log-softmax, T14 split staging -----
__global__ __launch_bounds__(512, 2)
void joint_main(const float* __restrict__ pe, const float* __restrict__ pd,
                const __bf16* __restrict__ pW, const float* __restrict__ bfc,
                const int* __restrict__ elens, const int* __restrict__ dlens,
                float* __restrict__ out)
{
  constexpr int BK = 128;
  __shared__ __align__(16) char As[2][64 * BK * 2];   // 32KB
  __shared__ float pr[8][64];
  __shared__ float lseS[64];

  const int blk = blockIdx.x;        // = b*T + t
  const int b = blk >> 8;
  const int t = blk & 255;
  const int tid = threadIdx.x;
  const int elen = elens[b], dlen = dlens[b];
  float* outBase = out + (size_t)blk * (UU * VV);

  if (t >= elen) {                   // whole 64x1024 tile masked -> zeros
    float4 z = {0.f, 0.f, 0.f, 0.f};
#pragma unroll 4
    for (int i = tid; i < UU * VV / 4; i += 512) ((float4*)outBase)[i] = z;
    return;
  }

  const int lane = tid & 63;
  const int wid  = tid >> 6;         // 0..7
  const int l31  = lane & 31;
  const int lhi  = lane >> 5;
  const int colLane = wid * 128 + l31;

  const float* peRow  = pe + (size_t)blk * FF;
  const float* pdBase = pd + (size_t)b * UU * FF;

  const int sr = tid >> 4;           // staging row base (0..31)
  const int sg = tid & 15;           // k-group of 8

  // T14 split staging: issue loads early, tanh+LDS-commit late.
  float4 R[4];
  auto issueH = [&](int kc, int half) {
    int r = sr + half * 32;
    int k = kc * BK + sg * 8;
    const float4* e4 = (const float4*)(peRow + k);
    const float4* d4 = (const float4*)(pdBase + (size_t)r * FF + k);
    R[0] = e4[0]; R[1] = e4[1]; R[2] = d4[0]; R[3] = d4[1];
  };
  auto commitH = [&](int buf, int half) {
    int r = sr + half * 32;
    float hv[8] = {R[0].x + R[2].x, R[0].y + R[2].y, R[0].z + R[2].z, R[0].w + R[2].w,
                   R[1].x + R[3].x, R[1].y + R[3].y, R[1].z + R[3].z, R[1].w + R[3].w};
    bf16x8 p;
#pragma unroll
    for (int q = 0; q < 8; ++q) p[q] = (__bf16)fast_tanh(hv[q]);
    *(bf16x8*)(&As[buf][r * (BK * 2) + ((sg * 16) ^ ((r & 7) << 4))]) = p;
  };

  f32x16 acc[2][4];
#pragma unroll
  for (int mi = 0; mi < 2; ++mi)
#pragma unroll
    for (int ni = 0; ni < 4; ++ni)
#pragma unroll
      for (int q = 0; q < 16; ++q) acc[mi][ni][q] = 0.f;

  issueH(0, 0); commitH(0, 0);
  issueH(0, 1); commitH(0, 1);
  __syncthreads();

  auto mstep = [&](const char* Ab, int kc, int ks) {
    int k8 = (kc * 8 + ks) * 2 + lhi;
    bf16x8 bfr[4];
#pragma unroll
    for (int ni = 0; ni < 4; ++ni)
      bfr[ni] = *(const bf16x8*)(pW + ((size_t)k8 * VV + colLane + ni * 32) * 8);
    bf16x8 afr[2];
#pragma unroll
    for (int mi = 0; mi < 2; ++mi) {
      int ra = mi * 32 + l31;
      int kb = ks * 32 + lhi * 16;
      afr[mi] = *(const bf16x8*)(&Ab[ra * (BK * 2) + (kb ^ ((ra & 7) << 4))]);
    }
#pragma unroll
    for (int mi = 0; mi < 2; ++mi)
#pragma unroll
      for (int ni = 0; ni < 4; ++ni)
        acc[mi][ni] = __builtin_amdgcn_mfma_f32_32x32x16_bf16(afr[mi], bfr[ni], acc[mi][ni], 0, 0, 0);
  };

  for (int kc = 0; kc < FF / BK; ++kc) {   // 8 chunks of BK=128
    const char* Ab = As[kc & 1];
    const int nb = (kc + 1) & 1;
    const bool more = (kc + 1) < FF / BK;
    if (more) issueH(kc + 1, 0);           // loads fly over next ~32 MFMAs
#pragma unroll
    for (int ks = 0; ks < 4; ++ks) mstep(Ab, kc, ks);
    if (more) { commitH(nb, 0); issueH(kc + 1, 1); }
#pragma unroll
    for (int ks = 4; ks < 8; ++ks) mstep(Ab, kc, ks);
    if (more) commitH(nb, 1);
    __syncthreads();                       // one barrier per chunk
  }

  // bias + exp row-sums (max-free: |logit| <= 1024/32 + |b_fc| < 33, exp fits fp32)
  float bias[4];
#pragma unroll
  for (int ni = 0; ni < 4; ++ni) bias[ni] = bfc[colLane + ni * 32];

  float rsum[2][16];
#pragma unroll
  for (int mi = 0; mi < 2; ++mi)
#pragma unroll
    for (int j = 0; j < 16; ++j) {
      float s = 0.f;
#pragma unroll
      for (int ni = 0; ni < 4; ++ni) {
        float v = acc[mi][ni][j] + bias[ni];
        acc[mi][ni][j] = v;
        s += __expf(v);
      }
      rsum[mi][j] = s;
    }
#pragma unroll
  for (int s = 1; s < 32; s <<= 1) {
#pragma unroll
    for (int mi = 0; mi < 2; ++mi)
#pragma unroll
      for (int j = 0; j < 16; ++j)
        rsum[mi][j] += __shfl_xor(rsum[mi][j], s, 64);
  }
#pragma unroll
  for (int mi = 0; mi < 2; ++mi)
#pragma unroll
    for (int j = 0; j < 16; ++j)
      if (l31 == j) {
        int row = mi * 32 + (j & 3) + 8 * (j >> 2) + 4 * lhi;
        pr[wid][row] = rsum[mi][j];
      }
  __syncthreads();
  if (tid < 64) {
    float s = 0.f;
#pragma unroll
    for (int w = 0; w < 8; ++w) s += pr[w][tid];
    lseS[tid] = __logf(s);
  }
  __syncthreads();

#pragma unroll
  for (int mi = 0; mi < 2; ++mi)
#pragma unroll
    for (int j = 0; j < 16; ++j) {
      int row = mi * 32 + (j & 3) + 8 * (j >> 2) + 4 * lhi;
      float l = lseS[row];
      bool valid = row < dlen;
#pragma unroll
      for (int ni = 0; ni < 4; ++ni) {
        float v = valid ? (acc[mi][ni][j] - l) : 0.0f;
        outBase[(size_t)row * VV + colLane + ni * 32] = v;
      }
    }
}

extern "C" void kernel_launch(void* const* d_in, const int* in_sizes, int n_in,
                              void* d_out, int out_size, void* d_ws, size_t ws_size,
                              hipStream_t stream)
{
  const float* enc  = (const float*)d_in[0];
  const float* dec  = (const float*)d_in[1];
  const float* Wenc = (const float*)d_in[2];
  const float* benc = (const float*)d_in[3];
  const float* Wdec = (const float*)d_in[4];
  const float* bdec = (const float*)d_in[5];
  const float* Wfc  = (const float*)d_in[6];
  const float* bfc  = (const float*)d_in[7];
  const int* elens  = (const int*)d_in[8];
  const int* dlens  = (const int*)d_in[9];
  float* out = (float*)d_out;

  float* pe = (float*)d_ws;                       // 1024*1024 f32
  float* pd = pe + 1024 * 1024;                   // 256*1024 f32
  __bf16* Pfc = (__bf16*)(pd + 256 * 1024);       // 1024*1024 bf16
  __bf16* Pen = Pfc + 1024 * 1024;                // 512*1024 bf16
  __bf16* Pde = Pen + 512 * 1024;                 // 512*1024 bf16

  pack_w<<<1024, 256, 0, stream>>>(Wfc, Wenc, Wdec, Pfc, Pen, Pde);
  proj_mfma<<<80, 256, 0, stream>>>(enc, dec, Pen, Pde, benc, bdec, pe, pd);
  joint_main<<<1024, 512, 0, stream>>>(pe, pd, Pfc, bfc, elens, dlens, out);
}